// Round 6
// baseline (260.626 us; speedup 1.0000x reference)
//
#include <hip/hip_runtime.h>
#include <math.h>

#define BATCH 8192
#define SENTS 50
#define ED    256
#define NENT  20
#define BB    16
#define TOTAL_WAVES 4096

// log2(200)/256
#define RATE_K 0.0298588132413075f

// ---------------------------------------------------------------------------
// Kernel S: one WAVE per batch, zero barriers, zero LDS. Lane c owns float4
// columns [4c..4c+3]. Rows stream through a depth-8 register ring with
// online softmax (flash-style): x consumed at arrival, never stored.
// Entities reduced in 4-load groups. Each wave does 2 batches (fully
// resident grid: 1024 blocks x 4 waves = 4096 waves).
// ---------------------------------------------------------------------------
__global__ __launch_bounds__(256, 4) void stream_kernel(
    const float* __restrict__ sents, const float* __restrict__ entities,
    const float* __restrict__ dense_w,
    float* __restrict__ h_out, float* __restrict__ m_out)
{
    int t   = threadIdx.x;
    int c   = t & 63;
    int sr  = t >> 6;
    int wid = blockIdx.x * 4 + sr;

    // per-lane rates for columns 4c..4c+3 (pure VALU, once)
    float4 rate;
    rate.x = exp2f(-(float)(4 * c + 0) * RATE_K);
    rate.y = exp2f(-(float)(4 * c + 1) * RATE_K);
    rate.z = exp2f(-(float)(4 * c + 2) * RATE_K);
    rate.w = exp2f(-(float)(4 * c + 3) * RATE_K);
    float4 w4 = ((const float4*)dense_w)[c];

    #pragma unroll 1
    for (int rep = 0; rep < 2; ++rep) {
        int b = wid + rep * TOTAL_WAVES;
        const float4* s4 = (const float4*)(sents + (size_t)b * SENTS * ED);
        const float4* e4 = (const float4*)(entities + (size_t)b * NENT * ED);

        // ---- entity sum: 5 groups of 4 loads (bounded reg pressure) ----
        float4 es = make_float4(0.f, 0.f, 0.f, 0.f);
        #pragma unroll
        for (int g = 0; g < 5; ++g) {
            float4 t0 = e4[(4 * g + 0) * 64 + c];
            float4 t1 = e4[(4 * g + 1) * 64 + c];
            float4 t2 = e4[(4 * g + 2) * 64 + c];
            float4 t3 = e4[(4 * g + 3) * 64 + c];
            es.x += (t0.x + t1.x) + (t2.x + t3.x);
            es.y += (t0.y + t1.y) + (t2.y + t3.y);
            es.z += (t0.z + t1.z) + (t2.z + t3.z);
            es.w += (t0.w + t1.w) + (t2.w + t3.w);
        }

        // ---- q = sents[49] + pos[49] ----
        float4 qv = s4[49 * 64 + c];
        float4 q;
        q.x = qv.x + __sinf(49.f * rate.x);
        q.y = qv.y + __sinf(49.f * rate.y);
        q.z = qv.z + __sinf(49.f * rate.z);
        q.w = qv.w + __sinf(49.f * rate.w);

        // ---- warm the prefetch ring (rows 0..7) ----
        float4 buf[8];
        #pragma unroll
        for (int k = 0; k < 8; ++k) buf[k] = s4[k * 64 + c];

        // ---- stream 50 rows, online softmax ----
        float  mrun = -INFINITY;
        float  drun = 0.f;
        float4 h = make_float4(0.f, 0.f, 0.f, 0.f);
        #pragma unroll
        for (int s = 0; s < SENTS; ++s) {
            float4 xv = buf[s & 7];
            if (s + 8 < SENTS) buf[s & 7] = s4[(s + 8) * 64 + c];  // prefetch

            float fs = (float)s;
            float4 x;
            x.x = xv.x + __sinf(fs * rate.x);
            x.y = xv.y + __sinf(fs * rate.y);
            x.z = xv.z + __sinf(fs * rate.z);
            x.w = xv.w + __sinf(fs * rate.w);

            float p = x.x * q.x + x.y * q.y + x.z * q.z + x.w * q.w;
            p += __shfl_xor(p, 1);
            p += __shfl_xor(p, 2);
            p += __shfl_xor(p, 4);
            p += __shfl_xor(p, 8);
            p += __shfl_xor(p, 16);
            p += __shfl_xor(p, 32);

            float mnew = fmaxf(mrun, p);
            float sc   = __expf(mrun - mnew);   // 0 on first iter (-inf)
            float wgt  = __expf(p - mnew);
            h.x = h.x * sc + wgt * x.x;
            h.y = h.y * sc + wgt * x.y;
            h.z = h.z * sc + wgt * x.z;
            h.w = h.w * sc + wgt * x.w;
            drun = drun * sc + wgt;
            mrun = mnew;
        }

        float inv = 1.f / drun;
        h.x *= inv; h.y *= inv; h.z *= inv; h.w *= inv;
        ((float4*)(h_out + (size_t)b * ED))[c] = h;

        float4 m;
        m.x = es.x * w4.x; m.y = es.y * w4.y;
        m.z = es.z * w4.z; m.w = es.w * w4.w;
        ((float4*)(m_out + (size_t)b * ED))[c] = m;
    }
}

// ---------------------------------------------------------------------------
// Kernel 2: out[b] = sigmoid( sum_e (sum_e' h[e'] A[e',e]) * m[e] + bias )
// BB batches per block; coalesced column reads of A (L2-resident).
// ---------------------------------------------------------------------------
__global__ __launch_bounds__(256) void bilinear_kernel(
    const float* __restrict__ hws, const float* __restrict__ mws,
    const float* __restrict__ A, const float* __restrict__ dense_b,
    float* __restrict__ out)
{
    __shared__ __align__(16) float hl[BB][ED];
    __shared__ float ml[BB][ED];
    __shared__ float part[BB][ED];

    int t  = threadIdx.x;
    int b0 = blockIdx.x * BB;

    for (int i = 0; i < BB; ++i) {
        hl[i][t] = hws[(size_t)(b0 + i) * ED + t];
        ml[i][t] = mws[(size_t)(b0 + i) * ED + t];
    }
    __syncthreads();

    float acc[BB];
    #pragma unroll
    for (int i = 0; i < BB; ++i) acc[i] = 0.f;

    for (int ep = 0; ep < ED; ep += 4) {
        float a0 = A[(ep + 0) * ED + t];
        float a1 = A[(ep + 1) * ED + t];
        float a2 = A[(ep + 2) * ED + t];
        float a3 = A[(ep + 3) * ED + t];
        #pragma unroll
        for (int i = 0; i < BB; ++i) {
            float4 hv = *(const float4*)&hl[i][ep];
            acc[i] += hv.x * a0 + hv.y * a1 + hv.z * a2 + hv.w * a3;
        }
    }

    #pragma unroll
    for (int i = 0; i < BB; ++i) part[i][t] = acc[i] * ml[i][t];
    __syncthreads();

    int lane = t & 63, w = t >> 6;
    float bias = dense_b[0];
    for (int i = w; i < BB; i += 4) {
        float v = part[i][lane] + part[i][lane + 64] + part[i][lane + 128] + part[i][lane + 192];
        for (int off = 32; off >= 1; off >>= 1) v += __shfl_xor(v, off);
        if (lane == 0) out[b0 + i] = 1.f / (1.f + expf(-(v + bias)));
    }
}

// ---------------------------------------------------------------------------
// Fallback: fully fused, no workspace (in case ws_size is tiny)
// ---------------------------------------------------------------------------
__global__ __launch_bounds__(256) void fused_kernel(
    const float* __restrict__ sents, const float* __restrict__ entities,
    const float* __restrict__ A, const float* __restrict__ dense_w,
    const float* __restrict__ dense_b, float* __restrict__ out)
{
    __shared__ __align__(16) float xs[SENTS][ED + 4];
    __shared__ float logit_s[64];
    __shared__ float coef[64];
    __shared__ __align__(16) float harr[ED];
    __shared__ float marr[ED];
    __shared__ float red[4];

    int t    = threadIdx.x;
    int b    = blockIdx.x;
    int lane = t & 63;
    int w    = t >> 6;

    float rate = exp2f(-(float)t * RATE_K);
    const float* sp = sents + (size_t)b * SENTS * ED;
    for (int s = 0; s < SENTS; ++s)
        xs[s][t] = sp[s * ED + t] + sinf((float)s * rate);
    __syncthreads();

    float4 q = *(const float4*)&xs[SENTS - 1][lane * 4];
    for (int s = w; s < SENTS; s += 4) {
        float4 v = *(const float4*)&xs[s][lane * 4];
        float p = v.x * q.x + v.y * q.y + v.z * q.z + v.w * q.w;
        p += __shfl_down(p, 32);
        p += __shfl_down(p, 16);
        p += __shfl_down(p, 8);
        p += __shfl_down(p, 4);
        p += __shfl_down(p, 2);
        p += __shfl_down(p, 1);
        if (lane == 0) logit_s[s] = p;
    }
    __syncthreads();

    if (w == 0) {
        float l = (lane < SENTS) ? logit_s[lane] : -INFINITY;
        float mx = l;
        for (int off = 32; off >= 1; off >>= 1) mx = fmaxf(mx, __shfl_xor(mx, off));
        float ex = (lane < SENTS) ? expf(l - mx) : 0.f;
        float sm = ex;
        for (int off = 32; off >= 1; off >>= 1) sm += __shfl_xor(sm, off);
        if (lane < SENTS) coef[lane] = ex / sm;
    }
    __syncthreads();

    float h = 0.f;
    #pragma unroll
    for (int s = 0; s < SENTS; ++s) h += coef[s] * xs[s][t];

    const float* ent = entities + (size_t)b * NENT * ED;
    float es = 0.f;
    #pragma unroll
    for (int n = 0; n < NENT; ++n) es += ent[n * ED + t];
    float m = es * dense_w[t];

    harr[t] = h;
    marr[t] = m;
    __syncthreads();

    float acc = 0.f;
    for (int ep = 0; ep < ED; ep += 4) {
        float4 hv = *(const float4*)&harr[ep];
        acc += hv.x * A[(ep + 0) * ED + t];
        acc += hv.y * A[(ep + 1) * ED + t];
        acc += hv.z * A[(ep + 2) * ED + t];
        acc += hv.w * A[(ep + 3) * ED + t];
    }
    float val = acc * marr[t];
    val += __shfl_down(val, 32);
    val += __shfl_down(val, 16);
    val += __shfl_down(val, 8);
    val += __shfl_down(val, 4);
    val += __shfl_down(val, 2);
    val += __shfl_down(val, 1);
    if (lane == 0) red[w] = val;
    __syncthreads();
    if (t == 0) {
        float tot = red[0] + red[1] + red[2] + red[3];
        out[b] = 1.f / (1.f + expf(-(tot + dense_b[0])));
    }
}

extern "C" void kernel_launch(void* const* d_in, const int* in_sizes, int n_in,
                              void* d_out, int out_size, void* d_ws, size_t ws_size,
                              hipStream_t stream) {
    const float* sents    = (const float*)d_in[0];
    const float* entities = (const float*)d_in[1];
    const float* A        = (const float*)d_in[2];
    const float* dense_w  = (const float*)d_in[3];
    const float* dense_b  = (const float*)d_in[4];
    float* out = (float*)d_out;

    size_t hm_bytes = (size_t)BATCH * ED * sizeof(float);           // 8 MB each
    size_t need = 2 * hm_bytes;

    if (ws_size >= need) {
        float* hws = (float*)d_ws;
        float* mws = (float*)((char*)d_ws + hm_bytes);
        stream_kernel<<<TOTAL_WAVES / 4, 256, 0, stream>>>(sents, entities, dense_w, hws, mws);
        bilinear_kernel<<<BATCH / BB, 256, 0, stream>>>(hws, mws, A, dense_b, out);
    } else {
        fused_kernel<<<BATCH, 256, 0, stream>>>(sents, entities, A, dense_w, dense_b, out);
    }
}

// Round 7
// 149.371 us; speedup vs baseline: 1.7448x; 1.7448x over previous
//
#include <hip/hip_runtime.h>
#include <math.h>

#define BATCH 8192
#define SENTS 50
#define ED    256
#define NENT  20
#define BB    16

// log2(200)/256
#define RATE_K 0.0298588132413075f

// ---------------------------------------------------------------------------
// Kernel A: fused attention + entity reduce. 512 threads = 8 waves.
// Wave id sr = (r = sr>>1, h = sr&1): residue r owns rows s = r+4k
// (13 rows for r<2, 12 for r>=2); half h owns columns [128h .. 128h+127].
// Lane c owns float2 cols (128h+2c, +1). All loads float2, issued up front,
// static indices only. 2 barriers. All waves redundantly compute softmax.
// Target: <=64 VGPR -> 4 blocks/CU (32 waves, max occupancy).
// ---------------------------------------------------------------------------
__global__ __launch_bounds__(512, 8) void attn_ent_kernel(
    const float* __restrict__ sents, const float* __restrict__ entities,
    const float* __restrict__ dense_w,
    float* __restrict__ h_out, float* __restrict__ m_out)
{
    __shared__ float lgp[SENTS][2];                  // logit partials per half
    __shared__ __align__(8) float hpart[4][ED];      // h partials per residue
    __shared__ __align__(8) float epart[4][ED];      // ent partials per residue

    int t  = threadIdx.x;
    int b  = blockIdx.x;
    int c  = t & 63;
    int sr = t >> 6;          // 0..7
    int r  = sr >> 1;         // row residue 0..3
    int h  = sr & 1;          // column half 0..1
    int cp = 64 * h + c;      // float2 column-pair index 0..127

    const float2* s2 = (const float2*)(sents + (size_t)b * SENTS * ED);
    const float2* e2 = (const float2*)(entities + (size_t)b * NENT * ED);

    bool has13 = (r < 2);     // k=12 valid: rows 48 (r=0), 49 (r=1)

    // ---- issue ALL global loads up front (static destinations) ----
    float2 xv[13];
    #pragma unroll
    for (int k = 0; k < 12; ++k) xv[k] = s2[(r + 4 * k) * 128 + cp];
    float2 qsv = s2[49 * 128 + cp];
    float2 ev0 = e2[(r     ) * 128 + cp];
    float2 ev1 = e2[(r +  4) * 128 + cp];
    float2 ev2 = e2[(r +  8) * 128 + cp];
    float2 ev3 = e2[(r + 12) * 128 + cp];
    float2 ev4 = e2[(r + 16) * 128 + cp];
    if (has13) xv[12] = s2[(r + 48) * 128 + cp];

    // ---- per-lane rates (VALU overlaps load latency) ----
    float rx = exp2f(-(float)(2 * cp + 0) * RATE_K);
    float ry = exp2f(-(float)(2 * cp + 1) * RATE_K);

    // ---- q = sents[49] + pos[49] ----
    float2 q;
    q.x = qsv.x + __sinf(49.f * rx);
    q.y = qsv.y + __sinf(49.f * ry);

    // ---- entity partial sum ----
    float2 es;
    es.x = ((ev0.x + ev1.x) + (ev2.x + ev3.x)) + ev4.x;
    es.y = ((ev0.y + ev1.y) + (ev2.y + ev3.y)) + ev4.y;

    // ---- x = sents + pos; logit partials via 64-lane butterfly ----
    float2 x[13];
    #pragma unroll
    for (int k = 0; k < 13; ++k) {
        if (k < 12 || has13) {
            float fs = (float)(r + 4 * k);
            x[k].x = xv[k].x + __sinf(fs * rx);
            x[k].y = xv[k].y + __sinf(fs * ry);
            float p = x[k].x * q.x + x[k].y * q.y;
            p += __shfl_xor(p, 1);
            p += __shfl_xor(p, 2);
            p += __shfl_xor(p, 4);
            p += __shfl_xor(p, 8);
            p += __shfl_xor(p, 16);
            p += __shfl_xor(p, 32);
            if (c == 0) lgp[r + 4 * k][h] = p;
        } else {
            x[k] = make_float2(0.f, 0.f);
        }
    }
    __syncthreads();

    // ---- softmax over 50 logits: ALL waves compute redundantly ----
    float lg = (c < SENTS) ? (lgp[c][0] + lgp[c][1]) : -INFINITY;
    float mx = lg;
    mx = fmaxf(mx, __shfl_xor(mx, 1));
    mx = fmaxf(mx, __shfl_xor(mx, 2));
    mx = fmaxf(mx, __shfl_xor(mx, 4));
    mx = fmaxf(mx, __shfl_xor(mx, 8));
    mx = fmaxf(mx, __shfl_xor(mx, 16));
    mx = fmaxf(mx, __shfl_xor(mx, 32));
    float ex = (c < SENTS) ? __expf(lg - mx) : 0.f;
    float sm = ex;
    sm += __shfl_xor(sm, 1);
    sm += __shfl_xor(sm, 2);
    sm += __shfl_xor(sm, 4);
    sm += __shfl_xor(sm, 8);
    sm += __shfl_xor(sm, 16);
    sm += __shfl_xor(sm, 32);
    float coef = ex / sm;     // lane c holds coef[c] (c < 50)

    // ---- h partial: broadcast coef[r+4k] from lane r+4k, FMA into acc ----
    float2 hacc = make_float2(0.f, 0.f);
    #pragma unroll
    for (int k = 0; k < 13; ++k) {
        if (k < 12 || has13) {
            float cf = __shfl(coef, r + 4 * k);
            hacc.x += cf * x[k].x;
            hacc.y += cf * x[k].y;
        }
    }
    ((float2*)&hpart[r][2 * cp])[0] = hacc;
    ((float2*)&epart[r][2 * cp])[0] = es;
    __syncthreads();

    // ---- final reduce + write: threads 0..255 -> h, 256..511 -> m ----
    if (t < ED) {
        int e = t;
        float v = hpart[0][e] + hpart[1][e] + hpart[2][e] + hpart[3][e];
        h_out[(size_t)b * ED + e] = v;
    } else {
        int e = t - ED;
        float v = epart[0][e] + epart[1][e] + epart[2][e] + epart[3][e];
        m_out[(size_t)b * ED + e] = v * dense_w[e];
    }
}

// ---------------------------------------------------------------------------
// Kernel 2: out[b] = sigmoid( sum_e (sum_e' h[e'] A[e',e]) * m[e] + bias )
// BB batches per block; coalesced column reads of A (L2-resident).
// ---------------------------------------------------------------------------
__global__ __launch_bounds__(256) void bilinear_kernel(
    const float* __restrict__ hws, const float* __restrict__ mws,
    const float* __restrict__ A, const float* __restrict__ dense_b,
    float* __restrict__ out)
{
    __shared__ __align__(16) float hl[BB][ED];
    __shared__ float ml[BB][ED];
    __shared__ float part[BB][ED];

    int t  = threadIdx.x;
    int b0 = blockIdx.x * BB;

    for (int i = 0; i < BB; ++i) {
        hl[i][t] = hws[(size_t)(b0 + i) * ED + t];
        ml[i][t] = mws[(size_t)(b0 + i) * ED + t];
    }
    __syncthreads();

    float acc[BB];
    #pragma unroll
    for (int i = 0; i < BB; ++i) acc[i] = 0.f;

    for (int ep = 0; ep < ED; ep += 4) {
        float a0 = A[(ep + 0) * ED + t];
        float a1 = A[(ep + 1) * ED + t];
        float a2 = A[(ep + 2) * ED + t];
        float a3 = A[(ep + 3) * ED + t];
        #pragma unroll
        for (int i = 0; i < BB; ++i) {
            float4 hv = *(const float4*)&hl[i][ep];
            acc[i] += hv.x * a0 + hv.y * a1 + hv.z * a2 + hv.w * a3;
        }
    }

    #pragma unroll
    for (int i = 0; i < BB; ++i) part[i][t] = acc[i] * ml[i][t];
    __syncthreads();

    int lane = t & 63, w = t >> 6;
    float bias = dense_b[0];
    for (int i = w; i < BB; i += 4) {
        float v = part[i][lane] + part[i][lane + 64] + part[i][lane + 128] + part[i][lane + 192];
        for (int off = 32; off >= 1; off >>= 1) v += __shfl_xor(v, off);
        if (lane == 0) out[b0 + i] = 1.f / (1.f + expf(-(v + bias)));
    }
}

// ---------------------------------------------------------------------------
// Fallback: fully fused, no workspace (in case ws_size is tiny)
// ---------------------------------------------------------------------------
__global__ __launch_bounds__(256) void fused_kernel(
    const float* __restrict__ sents, const float* __restrict__ entities,
    const float* __restrict__ A, const float* __restrict__ dense_w,
    const float* __restrict__ dense_b, float* __restrict__ out)
{
    __shared__ __align__(16) float xs[SENTS][ED + 4];
    __shared__ float logit_s[64];
    __shared__ float coef[64];
    __shared__ __align__(16) float harr[ED];
    __shared__ float marr[ED];
    __shared__ float red[4];

    int t    = threadIdx.x;
    int b    = blockIdx.x;
    int lane = t & 63;
    int w    = t >> 6;

    float rate = exp2f(-(float)t * RATE_K);
    const float* sp = sents + (size_t)b * SENTS * ED;
    for (int s = 0; s < SENTS; ++s)
        xs[s][t] = sp[s * ED + t] + sinf((float)s * rate);
    __syncthreads();

    float4 q = *(const float4*)&xs[SENTS - 1][lane * 4];
    for (int s = w; s < SENTS; s += 4) {
        float4 v = *(const float4*)&xs[s][lane * 4];
        float p = v.x * q.x + v.y * q.y + v.z * q.z + v.w * q.w;
        p += __shfl_down(p, 32);
        p += __shfl_down(p, 16);
        p += __shfl_down(p, 8);
        p += __shfl_down(p, 4);
        p += __shfl_down(p, 2);
        p += __shfl_down(p, 1);
        if (lane == 0) logit_s[s] = p;
    }
    __syncthreads();

    if (w == 0) {
        float l = (lane < SENTS) ? logit_s[lane] : -INFINITY;
        float mx = l;
        for (int off = 32; off >= 1; off >>= 1) mx = fmaxf(mx, __shfl_xor(mx, off));
        float ex = (lane < SENTS) ? expf(l - mx) : 0.f;
        float sm = ex;
        for (int off = 32; off >= 1; off >>= 1) sm += __shfl_xor(sm, off);
        if (lane < SENTS) coef[lane] = ex / sm;
    }
    __syncthreads();

    float h = 0.f;
    #pragma unroll
    for (int s = 0; s < SENTS; ++s) h += coef[s] * xs[s][t];

    const float* ent = entities + (size_t)b * NENT * ED;
    float es = 0.f;
    #pragma unroll
    for (int n = 0; n < NENT; ++n) es += ent[n * ED + t];
    float m = es * dense_w[t];

    harr[t] = h;
    marr[t] = m;
    __syncthreads();

    float acc = 0.f;
    for (int ep = 0; ep < ED; ep += 4) {
        float4 hv = *(const float4*)&harr[ep];
        acc += hv.x * A[(ep + 0) * ED + t];
        acc += hv.y * A[(ep + 1) * ED + t];
        acc += hv.z * A[(ep + 2) * ED + t];
        acc += hv.w * A[(ep + 3) * ED + t];
    }
    float val = acc * marr[t];
    val += __shfl_down(val, 32);
    val += __shfl_down(val, 16);
    val += __shfl_down(val, 8);
    val += __shfl_down(val, 4);
    val += __shfl_down(val, 2);
    val += __shfl_down(val, 1);
    if (lane == 0) red[w] = val;
    __syncthreads();
    if (t == 0) {
        float tot = red[0] + red[1] + red[2] + red[3];
        out[b] = 1.f / (1.f + expf(-(tot + dense_b[0])));
    }
}

extern "C" void kernel_launch(void* const* d_in, const int* in_sizes, int n_in,
                              void* d_out, int out_size, void* d_ws, size_t ws_size,
                              hipStream_t stream) {
    const float* sents    = (const float*)d_in[0];
    const float* entities = (const float*)d_in[1];
    const float* A        = (const float*)d_in[2];
    const float* dense_w  = (const float*)d_in[3];
    const float* dense_b  = (const float*)d_in[4];
    float* out = (float*)d_out;

    size_t hm_bytes = (size_t)BATCH * ED * sizeof(float);           // 8 MB each
    size_t need = 2 * hm_bytes;

    if (ws_size >= need) {
        float* hws = (float*)d_ws;
        float* mws = (float*)((char*)d_ws + hm_bytes);
        attn_ent_kernel<<<BATCH, 512, 0, stream>>>(sents, entities, dense_w, hws, mws);
        bilinear_kernel<<<BATCH / BB, 256, 0, stream>>>(hws, mws, A, dense_b, out);
    } else {
        fused_kernel<<<BATCH, 256, 0, stream>>>(sents, entities, A, dense_w, dense_b, out);
    }
}